// Round 1
// baseline (8125.466 us; speedup 1.0000x reference)
//
#include <hip/hip_runtime.h>
#include <cmath>

#define BB 32
#define TT 24
#define NN 1024
#define FF 2
#define UU 16
#define HH 32
#define TFN 31

// ---- static device buffers (rewritten every call; no ws_size dependence) ----
__device__ float g_At[(size_t)BB*NN*NN];   // transposed adjacency: At[b][k][i] = A[b][i][k]
__device__ float g_h1[BB*NN*UU];
__device__ float g_h2[BB*NN*UU];
__device__ float g_ru[BB*NN*2*UU];         // ru_in (width 32)
__device__ float g_cin[BB*NN*UU];          // c_in (width 16)
__device__ float g_u[BB*NN*UU];            // u gate between ru- and c-kernels
__device__ float g_sin[BB*NN*FF];          // small_in for final GCN (width 2)
__device__ float g_c2[BB*FF];              // per-batch const: trend@Wt.T + feat@Wf.T

__device__ __forceinline__ float sigmf(float x) { return 1.0f/(1.0f+expf(-x)); }

// ---------------- transpose A -> g_At ----------------
__global__ __launch_bounds__(256)
void k_transpose(const float* __restrict__ A) {
  __shared__ float tile[32][33];
  int b  = blockIdx.z;
  int i0 = blockIdx.y*32;
  int j0 = blockIdx.x*32;
  int tx = threadIdx.x, ty = threadIdx.y;
  const float* Ab  = A    + (size_t)b*NN*NN;
  float*       Atb = g_At + (size_t)b*NN*NN;
#pragma unroll
  for (int r=0;r<32;r+=8) tile[ty+r][tx] = Ab[(size_t)(i0+ty+r)*NN + j0+tx];
  __syncthreads();
#pragma unroll
  for (int r=0;r<32;r+=8) Atb[(size_t)(j0+ty+r)*NN + i0+tx] = tile[tx][ty+r];
}

// ---------------- init: zero h1/h2, ru_in for step 0 (h=0) ----------------
__global__ __launch_bounds__(256)
void k_init(const float* __restrict__ recent,
            const float* __restrict__ rW1, const float* __restrict__ uW1) {
  int idx = blockIdx.x*256 + threadIdx.x;     // over B*N
  if (idx >= BB*NN) return;
  int b = idx >> 10, n = idx & (NN-1);
  float x0 = recent[((size_t)(b*TT)*NN + n)*FF + 0];
  float x1 = recent[((size_t)(b*TT)*NN + n)*FF + 1];
  float* ru = g_ru + (size_t)idx*32;
#pragma unroll
  for (int j=0;j<16;j++) ru[j]    = x0*rW1[j*18+0] + x1*rW1[j*18+1];
#pragma unroll
  for (int j=0;j<16;j++) ru[16+j] = x0*uW1[j*18+0] + x1*uW1[j*18+1];
  float* h1 = g_h1 + (size_t)idx*16;
  float* h2 = g_h2 + (size_t)idx*16;
#pragma unroll
  for (int j=0;j<16;j++) { h1[j]=0.f; h2[j]=0.f; }
}

// ---------------- 2-layer LSTM + ff feat + per-batch const2 ----------------
__global__ __launch_bounds__(128)
void k_lstm(const float* __restrict__ trend, const float* __restrict__ tfeat,
            const float* __restrict__ Wih0, const float* __restrict__ Whh0,
            const float* __restrict__ bih0, const float* __restrict__ bhh0,
            const float* __restrict__ Wih1, const float* __restrict__ Whh1,
            const float* __restrict__ bih1, const float* __restrict__ bhh1,
            const float* __restrict__ ffW, const float* __restrict__ ffb,
            const float* __restrict__ gcnW) {
  __shared__ float h[HH], c[HH], g[4*HH], hs0[TT][HH], tr[HH], fe[HH];
  int b = blockIdx.x, tid = threadIdx.x;
  if (tid < HH) { h[tid]=0.f; c[tid]=0.f; }
  __syncthreads();
  for (int t=0;t<TT;t++) {
    float x0 = trend[(b*TT+t)*FF+0], x1 = trend[(b*TT+t)*FF+1];
    float gv = bih0[tid] + bhh0[tid] + x0*Wih0[tid*FF+0] + x1*Wih0[tid*FF+1];
#pragma unroll
    for (int k=0;k<HH;k++) gv += h[k]*Whh0[tid*HH+k];
    g[tid] = gv;
    __syncthreads();
    if (tid < HH) {
      float ii = sigmf(g[tid]), ff = sigmf(g[HH+tid]);
      float gg = tanhf(g[2*HH+tid]), oo = sigmf(g[3*HH+tid]);
      float cn = ff*c[tid] + ii*gg;
      c[tid] = cn;
      float hn = oo*tanhf(cn);
      h[tid] = hn;
      hs0[t][tid] = hn;
    }
    __syncthreads();
  }
  if (tid < HH) { h[tid]=0.f; c[tid]=0.f; }
  __syncthreads();
  for (int t=0;t<TT;t++) {
    float gv = bih1[tid] + bhh1[tid];
#pragma unroll
    for (int k=0;k<HH;k++) gv += hs0[t][k]*Wih1[tid*HH+k];
#pragma unroll
    for (int k=0;k<HH;k++) gv += h[k]*Whh1[tid*HH+k];
    g[tid] = gv;
    __syncthreads();
    if (tid < HH) {
      float ii = sigmf(g[tid]), ff = sigmf(g[HH+tid]);
      float gg = tanhf(g[2*HH+tid]), oo = sigmf(g[3*HH+tid]);
      float cn = ff*c[tid] + ii*gg;
      c[tid] = cn;
      h[tid] = oo*tanhf(cn);
    }
    __syncthreads();
  }
  if (tid < HH) {
    tr[tid] = h[tid];
    float fv = ffb[tid];
#pragma unroll
    for (int j=0;j<TFN;j++) fv += tfeat[b*TFN+j]*ffW[tid*TFN+j];
    fe[tid] = fmaxf(fv, 0.f);
  }
  __syncthreads();
  if (tid < FF) {
    float s = 0.f;
#pragma unroll
    for (int j=0;j<HH;j++) s += tr[j]*gcnW[tid*80+16+j];
#pragma unroll
    for (int j=0;j<HH;j++) s += fe[j]*gcnW[tid*80+48+j];
    g_c2[b*FF+tid] = s;
  }
}

// ------------- width-32 GEMM: P=A@ru_in; epilogue: r,u, c_in -------------
// CELL=1: x from xp (recent slice, stride F), h=g_h1. CELL=2: x=g_h1, h=g_h2.
template<int FX, int CELL>
__global__ __launch_bounds__(256)
void k_gemm_ru(const float* __restrict__ xp,
               const float* __restrict__ rb, const float* __restrict__ ub,
               const float* __restrict__ cW) {
  __shared__ float Ys[64][32];
  __shared__ float P[128][33];
  int b  = blockIdx.y;
  int i0 = blockIdx.x*128;
  int tid = threadIdx.x;
  int tx = tid & 7, ty = tid >> 3;
  int c0 = tx*4, r0 = i0 + ty*4;
  const float* At = g_At + (size_t)b*NN*NN;
  const float* Y  = g_ru + (size_t)b*NN*32;
  float acc[4][4];
#pragma unroll
  for (int i=0;i<4;i++)
#pragma unroll
    for (int j=0;j<4;j++) acc[i][j]=0.f;
  for (int k0=0;k0<NN;k0+=64) {
    __syncthreads();
#pragma unroll
    for (int i=0;i<2;i++) {
      int p = tid + i*256;
      int row = p >> 3, col4 = (p & 7)*4;
      *(float4*)&Ys[row][col4] = *(const float4*)&Y[(size_t)(k0+row)*32 + col4];
    }
    __syncthreads();
#pragma unroll 8
    for (int kk=0;kk<64;kk++) {
      float4 av = *(const float4*)&At[(size_t)(k0+kk)*NN + r0];
      float4 yv = *(const float4*)&Ys[kk][c0];
      float a_[4] = {av.x,av.y,av.z,av.w};
      float y_[4] = {yv.x,yv.y,yv.z,yv.w};
#pragma unroll
      for (int i=0;i<4;i++)
#pragma unroll
        for (int j=0;j<4;j++) acc[i][j] = fmaf(a_[i], y_[j], acc[i][j]);
    }
  }
#pragma unroll
  for (int i=0;i<4;i++)
#pragma unroll
    for (int j=0;j<4;j++) P[ty*4+i][c0+j] = acc[i][j];
  __syncthreads();
  if (tid < 128) {
    int n = i0 + tid;
    int bn = b*NN + n;
    const float* hb = (CELL==1) ? (g_h1 + (size_t)bn*16) : (g_h2 + (size_t)bn*16);
    const float* xr = (CELL==1) ? (xp + (size_t)b*TT*NN*FF + (size_t)n*FF)
                                : (g_h1 + (size_t)bn*16);
    float rh[16], uu[16];
#pragma unroll
    for (int j=0;j<16;j++) {
      float rv = sigmf(P[tid][j] + rb[j]);
      uu[j] = sigmf(P[tid][16+j] + ub[j]);
      rh[j] = rv*hb[j];
    }
#pragma unroll
    for (int j=0;j<16;j++) g_u[(size_t)bn*16+j] = uu[j];
    float xv[FX];
#pragma unroll
    for (int f=0;f<FX;f++) xv[f] = xr[f];
    const int INS = FX + 16;
#pragma unroll
    for (int j=0;j<16;j++) {
      float s = 0.f;
#pragma unroll
      for (int f=0;f<FX;f++) s += xv[f]*cW[j*INS+f];
#pragma unroll
      for (int f=0;f<16;f++) s += rh[f]*cW[j*INS+FX+f];
      g_cin[(size_t)bn*16+j] = s;
    }
  }
}

// ------------- width-16 GEMM: P=A@c_in; epilogue: c,h_new + next ru_in -------------
// MODE 0: cell1 -> write g_h1, build ru_in for cell2 (xh=[h1_new,h2]), W stride 32
// MODE 1: cell2 -> write g_h2, build ru_in for cell1@t+1 (xh=[x_{t+1},h1]), W stride 18
// MODE 2: cell2 final -> write g_h2, build small_in = h2@Wr.T + const2
template<int MODE>
__global__ __launch_bounds__(128)
void k_gemm_c(const float* __restrict__ cb,
              const float* __restrict__ rWn, const float* __restrict__ uWn,
              const float* __restrict__ xnext, const float* __restrict__ gcnW) {
  __shared__ float Ys[64][16];
  __shared__ float P[128][17];
  int b = blockIdx.y, i0 = blockIdx.x*128, tid = threadIdx.x;
  int tx = tid & 3, ty = tid >> 2;
  int c0 = tx*4, r0 = i0 + ty*4;
  const float* At = g_At  + (size_t)b*NN*NN;
  const float* Y  = g_cin + (size_t)b*NN*16;
  float acc[4][4];
#pragma unroll
  for (int i=0;i<4;i++)
#pragma unroll
    for (int j=0;j<4;j++) acc[i][j]=0.f;
  for (int k0=0;k0<NN;k0+=64) {
    __syncthreads();
#pragma unroll
    for (int i=0;i<2;i++) {
      int p = tid + i*128;
      int row = p >> 2, col4 = (p & 3)*4;
      *(float4*)&Ys[row][col4] = *(const float4*)&Y[(size_t)(k0+row)*16 + col4];
    }
    __syncthreads();
#pragma unroll 8
    for (int kk=0;kk<64;kk++) {
      float4 av = *(const float4*)&At[(size_t)(k0+kk)*NN + r0];
      float4 yv = *(const float4*)&Ys[kk][c0];
      float a_[4] = {av.x,av.y,av.z,av.w};
      float y_[4] = {yv.x,yv.y,yv.z,yv.w};
#pragma unroll
      for (int i=0;i<4;i++)
#pragma unroll
        for (int j=0;j<4;j++) acc[i][j] = fmaf(a_[i], y_[j], acc[i][j]);
    }
  }
#pragma unroll
  for (int i=0;i<4;i++)
#pragma unroll
    for (int j=0;j<4;j++) P[ty*4+i][c0+j] = acc[i][j];
  __syncthreads();
  {
    int n = i0 + tid, bn = b*NN + n;
    float* hb = (MODE==0) ? (g_h1 + (size_t)bn*16) : (g_h2 + (size_t)bn*16);
    float hn[16];
#pragma unroll
    for (int j=0;j<16;j++) {
      float cv = tanhf(P[tid][j] + cb[j]);
      float uv = g_u[(size_t)bn*16+j];
      float ho = hb[j];
      hn[j] = uv*ho + (1.f-uv)*cv;
    }
#pragma unroll
    for (int j=0;j<16;j++) hb[j] = hn[j];
    if (MODE == 0) {
      float h2r[16];
#pragma unroll
      for (int f=0;f<16;f++) h2r[f] = g_h2[(size_t)bn*16+f];
#pragma unroll
      for (int j2=0;j2<32;j2++) {
        const float* W = (j2<16) ? (rWn + j2*32) : (uWn + (j2-16)*32);
        float s = 0.f;
#pragma unroll
        for (int f=0;f<16;f++) s += hn[f]*W[f];
#pragma unroll
        for (int f=0;f<16;f++) s += h2r[f]*W[16+f];
        g_ru[(size_t)bn*32+j2] = s;
      }
    } else if (MODE == 1) {
      const float* xr = xnext + (size_t)b*TT*NN*FF + (size_t)n*FF;
      float x0 = xr[0], x1 = xr[1];
      float h1r[16];
#pragma unroll
      for (int f=0;f<16;f++) h1r[f] = g_h1[(size_t)bn*16+f];
#pragma unroll
      for (int j2=0;j2<32;j2++) {
        const float* W = (j2<16) ? (rWn + j2*18) : (uWn + (j2-16)*18);
        float s = x0*W[0] + x1*W[1];
#pragma unroll
        for (int f=0;f<16;f++) s += h1r[f]*W[2+f];
        g_ru[(size_t)bn*32+j2] = s;
      }
    } else {
#pragma unroll
      for (int cc=0;cc<FF;cc++) {
        float s = g_c2[b*FF+cc];
#pragma unroll
        for (int f2=0;f2<16;f2++) s += hn[f2]*gcnW[cc*80+f2];
        g_sin[(size_t)bn*FF+cc] = s;
      }
    }
  }
}

// ---------------- final: out = tanh(A @ small_in + gcn_b) ----------------
__global__ __launch_bounds__(128)
void k_final(const float* __restrict__ gcnb, float* __restrict__ out) {
  int b = blockIdx.y;
  int r = blockIdx.x*128 + threadIdx.x;
  const float* At = g_At  + (size_t)b*NN*NN;
  const float* S  = g_sin + (size_t)b*NN*FF;
  float a0 = 0.f, a1 = 0.f;
#pragma unroll 8
  for (int k=0;k<NN;k++) {
    float a = At[(size_t)k*NN + r];
    a0 = fmaf(a, S[k*2+0], a0);
    a1 = fmaf(a, S[k*2+1], a1);
  }
  out[((size_t)b*NN + r)*FF + 0] = tanhf(a0 + gcnb[0]);
  out[((size_t)b*NN + r)*FF + 1] = tanhf(a1 + gcnb[1]);
}

extern "C" void kernel_launch(void* const* d_in, const int* in_sizes, int n_in,
                              void* d_out, int out_size, void* d_ws, size_t ws_size,
                              hipStream_t stream) {
  (void)in_sizes; (void)n_in; (void)d_ws; (void)ws_size; (void)out_size;
  const float* recent = (const float*)d_in[0];
  const float* trend  = (const float*)d_in[1];
  const float* A      = (const float*)d_in[2];
  const float* tfeat  = (const float*)d_in[3];
  const float* g1rW = (const float*)d_in[4];  const float* g1rb = (const float*)d_in[5];
  const float* g1uW = (const float*)d_in[6];  const float* g1ub = (const float*)d_in[7];
  const float* g1cW = (const float*)d_in[8];  const float* g1cb = (const float*)d_in[9];
  const float* g2rW = (const float*)d_in[10]; const float* g2rb = (const float*)d_in[11];
  const float* g2uW = (const float*)d_in[12]; const float* g2ub = (const float*)d_in[13];
  const float* g2cW = (const float*)d_in[14]; const float* g2cb = (const float*)d_in[15];
  const float* Wih0 = (const float*)d_in[16]; const float* Whh0 = (const float*)d_in[17];
  const float* bih0 = (const float*)d_in[18]; const float* bhh0 = (const float*)d_in[19];
  const float* Wih1 = (const float*)d_in[20]; const float* Whh1 = (const float*)d_in[21];
  const float* bih1 = (const float*)d_in[22]; const float* bhh1 = (const float*)d_in[23];
  const float* ffW  = (const float*)d_in[24]; const float* ffb  = (const float*)d_in[25];
  const float* gcnW = (const float*)d_in[26]; const float* gcnb = (const float*)d_in[27];
  float* out = (float*)d_out;

  k_transpose<<<dim3(32,32,32), dim3(32,8), 0, stream>>>(A);
  k_lstm<<<BB, 128, 0, stream>>>(trend, tfeat, Wih0, Whh0, bih0, bhh0,
                                 Wih1, Whh1, bih1, bhh1, ffW, ffb, gcnW);
  k_init<<<(BB*NN)/256, 256, 0, stream>>>(recent, g1rW, g1uW);

  for (int t=0; t<TT; t++) {
    // cell 1
    k_gemm_ru<2,1><<<dim3(8,BB), 256, 0, stream>>>(recent + (size_t)t*NN*FF, g1rb, g1ub, g1cW);
    k_gemm_c<0><<<dim3(8,BB), 128, 0, stream>>>(g1cb, g2rW, g2uW, nullptr, nullptr);
    // cell 2
    k_gemm_ru<16,2><<<dim3(8,BB), 256, 0, stream>>>(nullptr, g2rb, g2ub, g2cW);
    if (t < TT-1)
      k_gemm_c<1><<<dim3(8,BB), 128, 0, stream>>>(g2cb, g1rW, g1uW, recent + (size_t)(t+1)*NN*FF, nullptr);
    else
      k_gemm_c<2><<<dim3(8,BB), 128, 0, stream>>>(g2cb, nullptr, nullptr, nullptr, gcnW);
  }

  k_final<<<dim3(8,BB), 128, 0, stream>>>(gcnb, out);
}

// Round 2
// 7882.308 us; speedup vs baseline: 1.0308x; 1.0308x over previous
//
#include <hip/hip_runtime.h>
#include <cmath>

#define BB 32
#define TT 24
#define NN 1024
#define FF 2
#define UU 16
#define HH 32
#define TFN 31

// ---- static device buffers (rewritten every call) ----
__device__ float g_At[(size_t)BB*NN*NN];   // At[b][k][i] = A[b][i][k]
__device__ float g_h1[BB*NN*UU];
__device__ float g_h2[BB*NN*UU];
__device__ float g_ru[BB*NN*2*UU];         // ru_in (width 32)
__device__ float g_cin[BB*NN*UU];          // c_in (width 16)
__device__ float g_u[BB*NN*UU];            // u gate
__device__ float g_sin[BB*NN*FF];          // small_in for final GCN
__device__ float g_c2[BB*FF];              // per-batch const

__device__ __forceinline__ float sigmf(float x) { return 1.0f/(1.0f+expf(-x)); }

// ---------------- transpose A -> g_At ----------------
__global__ __launch_bounds__(256)
void k_transpose(const float* __restrict__ A) {
  __shared__ float tile[32][33];
  int b  = blockIdx.z;
  int i0 = blockIdx.y*32;
  int j0 = blockIdx.x*32;
  int tx = threadIdx.x, ty = threadIdx.y;
  const float* Ab  = A    + (size_t)b*NN*NN;
  float*       Atb = g_At + (size_t)b*NN*NN;
#pragma unroll
  for (int r=0;r<32;r+=8) tile[ty+r][tx] = Ab[(size_t)(i0+ty+r)*NN + j0+tx];
  __syncthreads();
#pragma unroll
  for (int r=0;r<32;r+=8) Atb[(size_t)(j0+ty+r)*NN + i0+tx] = tile[tx][ty+r];
}

// ---------------- init ----------------
__global__ __launch_bounds__(256)
void k_init(const float* __restrict__ recent,
            const float* __restrict__ rW1, const float* __restrict__ uW1) {
  int idx = blockIdx.x*256 + threadIdx.x;
  if (idx >= BB*NN) return;
  int b = idx >> 10, n = idx & (NN-1);
  float x0 = recent[((size_t)(b*TT)*NN + n)*FF + 0];
  float x1 = recent[((size_t)(b*TT)*NN + n)*FF + 1];
  float* ru = g_ru + (size_t)idx*32;
#pragma unroll
  for (int j=0;j<16;j++) ru[j]    = x0*rW1[j*18+0] + x1*rW1[j*18+1];
#pragma unroll
  for (int j=0;j<16;j++) ru[16+j] = x0*uW1[j*18+0] + x1*uW1[j*18+1];
  float* h1 = g_h1 + (size_t)idx*16;
  float* h2 = g_h2 + (size_t)idx*16;
#pragma unroll
  for (int j=0;j<16;j++) { h1[j]=0.f; h2[j]=0.f; }
}

// ---------------- LSTM + ff + const2 ----------------
__global__ __launch_bounds__(128)
void k_lstm(const float* __restrict__ trend, const float* __restrict__ tfeat,
            const float* __restrict__ Wih0, const float* __restrict__ Whh0,
            const float* __restrict__ bih0, const float* __restrict__ bhh0,
            const float* __restrict__ Wih1, const float* __restrict__ Whh1,
            const float* __restrict__ bih1, const float* __restrict__ bhh1,
            const float* __restrict__ ffW, const float* __restrict__ ffb,
            const float* __restrict__ gcnW) {
  __shared__ float h[HH], c[HH], g[4*HH], hs0[TT][HH], tr[HH], fe[HH];
  int b = blockIdx.x, tid = threadIdx.x;
  if (tid < HH) { h[tid]=0.f; c[tid]=0.f; }
  __syncthreads();
  for (int t=0;t<TT;t++) {
    float x0 = trend[(b*TT+t)*FF+0], x1 = trend[(b*TT+t)*FF+1];
    float gv = bih0[tid] + bhh0[tid] + x0*Wih0[tid*FF+0] + x1*Wih0[tid*FF+1];
#pragma unroll
    for (int k=0;k<HH;k++) gv += h[k]*Whh0[tid*HH+k];
    g[tid] = gv;
    __syncthreads();
    if (tid < HH) {
      float ii = sigmf(g[tid]), ff = sigmf(g[HH+tid]);
      float gg = tanhf(g[2*HH+tid]), oo = sigmf(g[3*HH+tid]);
      float cn = ff*c[tid] + ii*gg;
      c[tid] = cn;
      float hn = oo*tanhf(cn);
      h[tid] = hn;
      hs0[t][tid] = hn;
    }
    __syncthreads();
  }
  if (tid < HH) { h[tid]=0.f; c[tid]=0.f; }
  __syncthreads();
  for (int t=0;t<TT;t++) {
    float gv = bih1[tid] + bhh1[tid];
#pragma unroll
    for (int k=0;k<HH;k++) gv += hs0[t][k]*Wih1[tid*HH+k];
#pragma unroll
    for (int k=0;k<HH;k++) gv += h[k]*Whh1[tid*HH+k];
    g[tid] = gv;
    __syncthreads();
    if (tid < HH) {
      float ii = sigmf(g[tid]), ff = sigmf(g[HH+tid]);
      float gg = tanhf(g[2*HH+tid]), oo = sigmf(g[3*HH+tid]);
      float cn = ff*c[tid] + ii*gg;
      c[tid] = cn;
      h[tid] = oo*tanhf(cn);
    }
    __syncthreads();
  }
  if (tid < HH) {
    tr[tid] = h[tid];
    float fv = ffb[tid];
#pragma unroll
    for (int j=0;j<TFN;j++) fv += tfeat[b*TFN+j]*ffW[tid*TFN+j];
    fe[tid] = fmaxf(fv, 0.f);
  }
  __syncthreads();
  if (tid < FF) {
    float s = 0.f;
#pragma unroll
    for (int j=0;j<HH;j++) s += tr[j]*gcnW[tid*80+16+j];
#pragma unroll
    for (int j=0;j<HH;j++) s += fe[j]*gcnW[tid*80+48+j];
    g_c2[b*FF+tid] = s;
  }
}

// ------------- width-32 GEMM: P=A@ru_in; epilogue: r,u, c_in -------------
// 32-row tile, 128 threads, 4x2 micro-tile; grid (32, B) = 1024 blocks.
template<int FX, int CELL>
__global__ __launch_bounds__(128)
void k_gemm_ru(const float* __restrict__ xp,
               const float* __restrict__ rb, const float* __restrict__ ub,
               const float* __restrict__ cW) {
  __shared__ float Ys[64][32];
  __shared__ float P[32][33];
  __shared__ float RH[32][17];
  const int b   = blockIdx.y;
  const int i0  = blockIdx.x*32;
  const int tid = threadIdx.x;
  const int rg  = tid & 7;          // 8 row-groups of 4 rows
  const int cp  = tid >> 3;         // 16 col-pairs: cols {cp, cp+16}
  const int r0  = i0 + rg*4;
  const float* At = g_At + (size_t)b*NN*NN;
  const float* Y  = g_ru + (size_t)b*NN*32;
  float a00=0.f,a01=0.f,a10=0.f,a11=0.f,a20=0.f,a21=0.f,a30=0.f,a31=0.f;
  for (int k0=0;k0<NN;k0+=64) {
    __syncthreads();
#pragma unroll
    for (int q=0;q<4;q++) {
      int f4 = tid + q*128;
      *(float4*)&Ys[f4>>3][(f4&7)*4] =
          *(const float4*)&Y[(size_t)(k0 + (f4>>3))*32 + (f4&7)*4];
    }
    __syncthreads();
#pragma unroll 16
    for (int kk=0;kk<64;kk++) {
      float4 av = *(const float4*)&At[(size_t)(k0+kk)*NN + r0];
      float y0 = Ys[kk][cp], y1 = Ys[kk][cp+16];
      a00 = fmaf(av.x, y0, a00); a01 = fmaf(av.x, y1, a01);
      a10 = fmaf(av.y, y0, a10); a11 = fmaf(av.y, y1, a11);
      a20 = fmaf(av.z, y0, a20); a21 = fmaf(av.z, y1, a21);
      a30 = fmaf(av.w, y0, a30); a31 = fmaf(av.w, y1, a31);
    }
  }
  P[rg*4+0][cp] = a00; P[rg*4+0][cp+16] = a01;
  P[rg*4+1][cp] = a10; P[rg*4+1][cp+16] = a11;
  P[rg*4+2][cp] = a20; P[rg*4+2][cp+16] = a21;
  P[rg*4+3][cp] = a30; P[rg*4+3][cp+16] = a31;
  const int row = tid >> 2;         // 0..31
  const int jj  = tid & 3;          // handles j = jj*4 .. jj*4+3
  const int n   = i0 + row;
  const int bn  = b*NN + n;
  __syncthreads();
  {
    const float* hb = (CELL==1) ? (g_h1 + (size_t)bn*16) : (g_h2 + (size_t)bn*16);
    float4 hv = *(const float4*)&hb[jj*4];
    float h_[4] = {hv.x,hv.y,hv.z,hv.w};
    float u_[4];
#pragma unroll
    for (int q=0;q<4;q++) {
      int j = jj*4+q;
      float rv = sigmf(P[row][j] + rb[j]);
      u_[q] = sigmf(P[row][16+j] + ub[j]);
      RH[row][j] = rv*h_[q];
    }
    *(float4*)&g_u[(size_t)bn*16 + jj*4] = make_float4(u_[0],u_[1],u_[2],u_[3]);
  }
  __syncthreads();
  {
    const float* xr = (CELL==1) ? (xp + (size_t)b*TT*NN*FF + (size_t)n*FF)
                                : (g_h1 + (size_t)bn*16);
    float xv[FX];
#pragma unroll
    for (int f=0;f<FX;f++) xv[f] = xr[f];
    const int INS = FX + 16;
    float o[4];
#pragma unroll
    for (int q=0;q<4;q++) {
      int j = jj*4+q;
      float s = 0.f;
#pragma unroll
      for (int f=0;f<FX;f++) s = fmaf(xv[f], cW[j*INS+f], s);
#pragma unroll
      for (int f=0;f<16;f++) s = fmaf(RH[row][f], cW[j*INS+FX+f], s);
      o[q] = s;
    }
    *(float4*)&g_cin[(size_t)bn*16 + jj*4] = make_float4(o[0],o[1],o[2],o[3]);
  }
}

// ------------- width-16 GEMM: P=A@c_in; epilogue: h update + next inputs -------------
// 32-row tile, 128 threads, 2x2 micro-tile; grid (32, B) = 1024 blocks.
// MODE 0: cell1 -> g_h1, ru_in for cell2. MODE 1: cell2 -> g_h2, ru_in for t+1.
// MODE 2: cell2 final -> g_h2, small_in.
template<int MODE>
__global__ __launch_bounds__(128)
void k_gemm_c(const float* __restrict__ cb,
              const float* __restrict__ rWn, const float* __restrict__ uWn,
              const float* __restrict__ xnext, const float* __restrict__ gcnW) {
  __shared__ float Ys[64][16];
  __shared__ float P[32][17];
  __shared__ float HN[32][17];
  __shared__ float OTH[32][17];
  const int b   = blockIdx.y;
  const int i0  = blockIdx.x*32;
  const int tid = threadIdx.x;
  const int rg  = tid & 15;         // 16 row-groups of 2 rows
  const int cp  = tid >> 4;         // 8 col-pairs: cols {cp, cp+8}
  const int r0  = i0 + rg*2;
  const float* At = g_At  + (size_t)b*NN*NN;
  const float* Y  = g_cin + (size_t)b*NN*16;
  float a00=0.f,a01=0.f,a10=0.f,a11=0.f;
  for (int k0=0;k0<NN;k0+=64) {
    __syncthreads();
#pragma unroll
    for (int q=0;q<2;q++) {
      int f4 = tid + q*128;
      *(float4*)&Ys[f4>>2][(f4&3)*4] =
          *(const float4*)&Y[(size_t)(k0 + (f4>>2))*16 + (f4&3)*4];
    }
    __syncthreads();
#pragma unroll 16
    for (int kk=0;kk<64;kk++) {
      float2 av = *(const float2*)&At[(size_t)(k0+kk)*NN + r0];
      float y0 = Ys[kk][cp], y1 = Ys[kk][cp+8];
      a00 = fmaf(av.x, y0, a00); a01 = fmaf(av.x, y1, a01);
      a10 = fmaf(av.y, y0, a10); a11 = fmaf(av.y, y1, a11);
    }
  }
  P[rg*2+0][cp] = a00; P[rg*2+0][cp+8] = a01;
  P[rg*2+1][cp] = a10; P[rg*2+1][cp+8] = a11;
  const int row = tid >> 2;
  const int jj  = tid & 3;
  const int n   = i0 + row;
  const int bn  = b*NN + n;
  float* hb = (MODE==0) ? (g_h1 + (size_t)bn*16) : (g_h2 + (size_t)bn*16);
  __syncthreads();
  {
    float4 hov = *(const float4*)&hb[jj*4];
    float ho[4] = {hov.x,hov.y,hov.z,hov.w};
    float4 uv4 = *(const float4*)&g_u[(size_t)bn*16 + jj*4];
    float uv[4] = {uv4.x,uv4.y,uv4.z,uv4.w};
    float hn[4];
#pragma unroll
    for (int q=0;q<4;q++) {
      int j = jj*4+q;
      float cv = tanhf(P[row][j] + cb[j]);
      hn[q] = uv[q]*ho[q] + (1.f-uv[q])*cv;
      HN[row][j] = hn[q];
    }
    *(float4*)&hb[jj*4] = make_float4(hn[0],hn[1],hn[2],hn[3]);
    if (MODE == 0) {
      float4 o = *(const float4*)&g_h2[(size_t)bn*16 + jj*4];
      OTH[row][jj*4+0]=o.x; OTH[row][jj*4+1]=o.y;
      OTH[row][jj*4+2]=o.z; OTH[row][jj*4+3]=o.w;
    } else if (MODE == 1) {
      float4 o = *(const float4*)&g_h1[(size_t)bn*16 + jj*4];
      OTH[row][jj*4+0]=o.x; OTH[row][jj*4+1]=o.y;
      OTH[row][jj*4+2]=o.z; OTH[row][jj*4+3]=o.w;
    }
  }
  __syncthreads();
  if (MODE == 0) {
    float o[8];
#pragma unroll
    for (int m=0;m<8;m++) {
      int j2 = jj*8 + m;
      const float* W = (j2<16) ? (rWn + j2*32) : (uWn + (j2-16)*32);
      float s = 0.f;
#pragma unroll
      for (int f=0;f<16;f++) s = fmaf(HN[row][f], W[f], s);
#pragma unroll
      for (int f=0;f<16;f++) s = fmaf(OTH[row][f], W[16+f], s);
      o[m] = s;
    }
    *(float4*)&g_ru[(size_t)bn*32 + jj*8 + 0] = make_float4(o[0],o[1],o[2],o[3]);
    *(float4*)&g_ru[(size_t)bn*32 + jj*8 + 4] = make_float4(o[4],o[5],o[6],o[7]);
  } else if (MODE == 1) {
    const float* xr = xnext + (size_t)b*TT*NN*FF + (size_t)n*FF;
    float x0 = xr[0], x1 = xr[1];
    float o[8];
#pragma unroll
    for (int m=0;m<8;m++) {
      int j2 = jj*8 + m;
      const float* W = (j2<16) ? (rWn + j2*18) : (uWn + (j2-16)*18);
      float s = fmaf(x0, W[0], x1*W[1]);
#pragma unroll
      for (int f=0;f<16;f++) s = fmaf(OTH[row][f], W[2+f], s);
      o[m] = s;
    }
    *(float4*)&g_ru[(size_t)bn*32 + jj*8 + 0] = make_float4(o[0],o[1],o[2],o[3]);
    *(float4*)&g_ru[(size_t)bn*32 + jj*8 + 4] = make_float4(o[4],o[5],o[6],o[7]);
  } else {
    if (jj == 0) {
#pragma unroll
      for (int cc=0;cc<FF;cc++) {
        float s = g_c2[b*FF+cc];
#pragma unroll
        for (int f=0;f<16;f++) s = fmaf(HN[row][f], gcnW[cc*80+f], s);
        g_sin[(size_t)bn*FF+cc] = s;
      }
    }
  }
}

// ---------------- final: out = tanh(A @ small_in + gcn_b) ----------------
// 32-row tile, 8-way K split in block; grid (32, B) = 1024 blocks.
__global__ __launch_bounds__(256)
void k_final(const float* __restrict__ gcnb, float* __restrict__ out) {
  __shared__ float R0[8][32], R1[8][32];
  int b   = blockIdx.y;
  int i0  = blockIdx.x*32;
  int lane = threadIdx.x & 31, kc = threadIdx.x >> 5;
  int r = i0 + lane;
  const float* At = g_At  + (size_t)b*NN*NN;
  const float* S  = g_sin + (size_t)b*NN*FF;
  float a0 = 0.f, a1 = 0.f;
#pragma unroll 8
  for (int k=kc*128; k<(kc+1)*128; k++) {
    float a = At[(size_t)k*NN + r];
    a0 = fmaf(a, S[k*2+0], a0);
    a1 = fmaf(a, S[k*2+1], a1);
  }
  R0[kc][lane] = a0; R1[kc][lane] = a1;
  __syncthreads();
  if (threadIdx.x < 32) {
    float s0 = 0.f, s1 = 0.f;
#pragma unroll
    for (int q=0;q<8;q++) { s0 += R0[q][lane]; s1 += R1[q][lane]; }
    float2 o = make_float2(tanhf(s0 + gcnb[0]), tanhf(s1 + gcnb[1]));
    *(float2*)&out[((size_t)b*NN + i0 + lane)*FF] = o;
  }
}

extern "C" void kernel_launch(void* const* d_in, const int* in_sizes, int n_in,
                              void* d_out, int out_size, void* d_ws, size_t ws_size,
                              hipStream_t stream) {
  (void)in_sizes; (void)n_in; (void)d_ws; (void)ws_size; (void)out_size;
  const float* recent = (const float*)d_in[0];
  const float* trend  = (const float*)d_in[1];
  const float* A      = (const float*)d_in[2];
  const float* tfeat  = (const float*)d_in[3];
  const float* g1rW = (const float*)d_in[4];  const float* g1rb = (const float*)d_in[5];
  const float* g1uW = (const float*)d_in[6];  const float* g1ub = (const float*)d_in[7];
  const float* g1cW = (const float*)d_in[8];  const float* g1cb = (const float*)d_in[9];
  const float* g2rW = (const float*)d_in[10]; const float* g2rb = (const float*)d_in[11];
  const float* g2uW = (const float*)d_in[12]; const float* g2ub = (const float*)d_in[13];
  const float* g2cW = (const float*)d_in[14]; const float* g2cb = (const float*)d_in[15];
  const float* Wih0 = (const float*)d_in[16]; const float* Whh0 = (const float*)d_in[17];
  const float* bih0 = (const float*)d_in[18]; const float* bhh0 = (const float*)d_in[19];
  const float* Wih1 = (const float*)d_in[20]; const float* Whh1 = (const float*)d_in[21];
  const float* bih1 = (const float*)d_in[22]; const float* bhh1 = (const float*)d_in[23];
  const float* ffW  = (const float*)d_in[24]; const float* ffb  = (const float*)d_in[25];
  const float* gcnW = (const float*)d_in[26]; const float* gcnb = (const float*)d_in[27];
  float* out = (float*)d_out;

  k_transpose<<<dim3(32,32,32), dim3(32,8), 0, stream>>>(A);
  k_lstm<<<BB, 128, 0, stream>>>(trend, tfeat, Wih0, Whh0, bih0, bhh0,
                                 Wih1, Whh1, bih1, bhh1, ffW, ffb, gcnW);
  k_init<<<(BB*NN)/256, 256, 0, stream>>>(recent, g1rW, g1uW);

  for (int t=0; t<TT; t++) {
    // cell 1
    k_gemm_ru<2,1><<<dim3(32,BB), 128, 0, stream>>>(recent + (size_t)t*NN*FF, g1rb, g1ub, g1cW);
    k_gemm_c<0><<<dim3(32,BB), 128, 0, stream>>>(g1cb, g2rW, g2uW, nullptr, nullptr);
    // cell 2
    k_gemm_ru<16,2><<<dim3(32,BB), 128, 0, stream>>>(nullptr, g2rb, g2ub, g2cW);
    if (t < TT-1)
      k_gemm_c<1><<<dim3(32,BB), 128, 0, stream>>>(g2cb, g1rW, g1uW, recent + (size_t)(t+1)*NN*FF, nullptr);
    else
      k_gemm_c<2><<<dim3(32,BB), 128, 0, stream>>>(g2cb, nullptr, nullptr, nullptr, gcnW);
  }

  k_final<<<dim3(32,BB), 256, 0, stream>>>(gcnb, out);
}

// Round 3
// 2301.169 us; speedup vs baseline: 3.5310x; 3.4253x over previous
//
#include <hip/hip_runtime.h>
#include <cmath>
#include <stdint.h>

#define BB 32
#define TT 24
#define NN 1024
#define FF 2
#define UU 16
#define HH 32
#define TFN 31

typedef __attribute__((ext_vector_type(8))) short bf16x8;
typedef __attribute__((ext_vector_type(4))) float f32x4;
typedef unsigned short u16;
typedef unsigned int   u32;

// ---- static device buffers (fully rewritten every call) ----
__device__ __align__(16) u16 g_Ab [(size_t)BB*NN*NN];  // bf16 A, row-major [b][i][k]
__device__ __align__(16) u16 g_ru [(size_t)BB*32*NN];  // bf16 col-major [b][j][n]
__device__ __align__(16) u16 g_cin[(size_t)BB*16*NN];  // bf16 col-major [b][j][n]
__device__ __align__(16) u16 g_si [(size_t)BB*16*NN];  // bf16 col-major small_in (rows 2..15 zero)
__device__ float g_h1[BB*NN*UU];
__device__ float g_h2[BB*NN*UU];
__device__ float g_u [BB*NN*UU];
__device__ float g_c2[BB*FF];

__device__ __forceinline__ float sigmf(float x) { return 1.0f/(1.0f+expf(-x)); }
__device__ __forceinline__ u16 f2bf(float f) {      // RNE fp32 -> bf16
  u32 u = __float_as_uint(f);
  return (u16)((u + 0x7fffu + ((u >> 16) & 1u)) >> 16);
}

// ---------------- convert A fp32 -> bf16 (same layout) ----------------
__global__ __launch_bounds__(256)
void k_convert(const float* __restrict__ A) {
  size_t idx = ((size_t)blockIdx.x*256 + threadIdx.x)*8;
  float4 v0 = *(const float4*)(A + idx);
  float4 v1 = *(const float4*)(A + idx + 4);
  u32 p0 = (u32)f2bf(v0.x) | ((u32)f2bf(v0.y) << 16);
  u32 p1 = (u32)f2bf(v0.z) | ((u32)f2bf(v0.w) << 16);
  u32 p2 = (u32)f2bf(v1.x) | ((u32)f2bf(v1.y) << 16);
  u32 p3 = (u32)f2bf(v1.z) | ((u32)f2bf(v1.w) << 16);
  *(uint4*)&g_Ab[idx] = make_uint4(p0, p1, p2, p3);
}

// ---------------- init: zero h1/h2, ru_in (col-major bf16) for step 0 ----------------
__global__ __launch_bounds__(256)
void k_init(const float* __restrict__ recent,
            const float* __restrict__ rW1, const float* __restrict__ uW1) {
  int idx = blockIdx.x*256 + threadIdx.x;
  if (idx >= BB*NN) return;
  int b = idx >> 10, n = idx & (NN-1);
  float x0 = recent[((size_t)(b*TT)*NN + n)*FF + 0];
  float x1 = recent[((size_t)(b*TT)*NN + n)*FF + 1];
#pragma unroll
  for (int j=0;j<16;j++)
    g_ru[(((size_t)b*32 + j)<<10) + n]      = f2bf(x0*rW1[j*18+0] + x1*rW1[j*18+1]);
#pragma unroll
  for (int j=0;j<16;j++)
    g_ru[(((size_t)b*32 + 16 + j)<<10) + n] = f2bf(x0*uW1[j*18+0] + x1*uW1[j*18+1]);
  float* h1 = g_h1 + (size_t)idx*16;
  float* h2 = g_h2 + (size_t)idx*16;
#pragma unroll
  for (int j=0;j<16;j++) { h1[j]=0.f; h2[j]=0.f; }
}

// ---------------- LSTM + ff + const2 (unchanged, tiny) ----------------
__global__ __launch_bounds__(128)
void k_lstm(const float* __restrict__ trend, const float* __restrict__ tfeat,
            const float* __restrict__ Wih0, const float* __restrict__ Whh0,
            const float* __restrict__ bih0, const float* __restrict__ bhh0,
            const float* __restrict__ Wih1, const float* __restrict__ Whh1,
            const float* __restrict__ bih1, const float* __restrict__ bhh1,
            const float* __restrict__ ffW, const float* __restrict__ ffb,
            const float* __restrict__ gcnW) {
  __shared__ float h[HH], c[HH], g[4*HH], hs0[TT][HH], tr[HH], fe[HH];
  int b = blockIdx.x, tid = threadIdx.x;
  if (tid < HH) { h[tid]=0.f; c[tid]=0.f; }
  __syncthreads();
  for (int t=0;t<TT;t++) {
    float x0 = trend[(b*TT+t)*FF+0], x1 = trend[(b*TT+t)*FF+1];
    float gv = bih0[tid] + bhh0[tid] + x0*Wih0[tid*FF+0] + x1*Wih0[tid*FF+1];
#pragma unroll
    for (int k=0;k<HH;k++) gv += h[k]*Whh0[tid*HH+k];
    g[tid] = gv;
    __syncthreads();
    if (tid < HH) {
      float ii = sigmf(g[tid]), ff = sigmf(g[HH+tid]);
      float gg = tanhf(g[2*HH+tid]), oo = sigmf(g[3*HH+tid]);
      float cn = ff*c[tid] + ii*gg;
      c[tid] = cn;
      float hn = oo*tanhf(cn);
      h[tid] = hn;
      hs0[t][tid] = hn;
    }
    __syncthreads();
  }
  if (tid < HH) { h[tid]=0.f; c[tid]=0.f; }
  __syncthreads();
  for (int t=0;t<TT;t++) {
    float gv = bih1[tid] + bhh1[tid];
#pragma unroll
    for (int k=0;k<HH;k++) gv += hs0[t][k]*Wih1[tid*HH+k];
#pragma unroll
    for (int k=0;k<HH;k++) gv += h[k]*Whh1[tid*HH+k];
    g[tid] = gv;
    __syncthreads();
    if (tid < HH) {
      float ii = sigmf(g[tid]), ff = sigmf(g[HH+tid]);
      float gg = tanhf(g[2*HH+tid]), oo = sigmf(g[3*HH+tid]);
      float cn = ff*c[tid] + ii*gg;
      c[tid] = cn;
      h[tid] = oo*tanhf(cn);
    }
    __syncthreads();
  }
  if (tid < HH) {
    tr[tid] = h[tid];
    float fv = ffb[tid];
#pragma unroll
    for (int j=0;j<TFN;j++) fv += tfeat[b*TFN+j]*ffW[tid*TFN+j];
    fe[tid] = fmaxf(fv, 0.f);
  }
  __syncthreads();
  if (tid < FF) {
    float s = 0.f;
#pragma unroll
    for (int j=0;j<HH;j++) s += tr[j]*gcnW[tid*80+16+j];
#pragma unroll
    for (int j=0;j<HH;j++) s += fe[j]*gcnW[tid*80+48+j];
    g_c2[b*FF+tid] = s;
  }
}

// ------------- MFMA width-32 pass: P = A @ ru_in; epilogue r,u,c_in -------------
// 32-row tile, 128 threads (2 waves), BK=128; grid (32, B).
template<int FX, int CELL>
__global__ __launch_bounds__(128)
void k_mm32(const float* __restrict__ xp,
            const float* __restrict__ rb, const float* __restrict__ ub,
            const float* __restrict__ cW) {
  __shared__ u16 As[32][136];   // A tile [i][k], pad 8
  __shared__ u16 Ys[32][136];   // Y tile [j][k], pad 8
  __shared__ float P[32][33];
  __shared__ float RH[32][17];
  const int b = blockIdx.y, i0 = blockIdx.x*32, tid = threadIdx.x;
  const int w = tid >> 6, lane = tid & 63, m = lane & 15, quad = lane >> 4;
  const size_t Abase = ((size_t)b*NN + i0)*NN;
  const u16* Yg = g_ru + ((size_t)b*32)*NN;
  const int srow = tid >> 2, sq = tid & 3;
  f32x4 acc0 = {0.f,0.f,0.f,0.f}, acc1 = {0.f,0.f,0.f,0.f};

  for (int k0=0;k0<NN;k0+=128) {
    __syncthreads();
#pragma unroll
    for (int q=0;q<4;q++) {
      int off = sq*8 + q*32;
      *(uint4*)&As[srow][off] = *(const uint4*)&g_Ab[Abase + (size_t)srow*NN + k0 + off];
    }
#pragma unroll
    for (int q=0;q<4;q++) {
      int off = sq*8 + q*32;
      *(uint4*)&Ys[srow][off] = *(const uint4*)&Yg[(size_t)srow*NN + k0 + off];
    }
    __syncthreads();
#pragma unroll
    for (int s=0;s<4;s++) {
      bf16x8 af = *(const bf16x8*)&As[w*16 + m][s*32 + quad*8];
      bf16x8 b0 = *(const bf16x8*)&Ys[m]       [s*32 + quad*8];
      bf16x8 b1 = *(const bf16x8*)&Ys[16 + m]  [s*32 + quad*8];
      acc0 = __builtin_amdgcn_mfma_f32_16x16x32_bf16(af, b0, acc0, 0, 0, 0);
      acc1 = __builtin_amdgcn_mfma_f32_16x16x32_bf16(af, b1, acc1, 0, 0, 0);
    }
  }
#pragma unroll
  for (int r=0;r<4;r++) {
    P[w*16 + quad*4 + r][m]      = acc0[r];
    P[w*16 + quad*4 + r][16 + m] = acc1[r];
  }
  __syncthreads();
  // epilogue: 4 threads per row, 4 gate-indices each
  const int row = tid >> 2, jj = tid & 3, n = i0 + row, bn = b*NN + n;
  {
    const float* hb = (CELL==1) ? &g_h1[(size_t)bn*16] : &g_h2[(size_t)bn*16];
    float4 hv = *(const float4*)&hb[jj*4];
    float h_[4] = {hv.x,hv.y,hv.z,hv.w};
    float u_[4];
#pragma unroll
    for (int q=0;q<4;q++) {
      int j = jj*4+q;
      float rv = sigmf(P[row][j] + rb[j]);
      u_[q] = sigmf(P[row][16+j] + ub[j]);
      RH[row][j] = rv*h_[q];
    }
    *(float4*)&g_u[(size_t)bn*16 + jj*4] = make_float4(u_[0],u_[1],u_[2],u_[3]);
  }
  __syncthreads();
  {
    const float* xr = (CELL==1) ? (xp + (size_t)b*TT*NN*FF + (size_t)n*FF)
                                : &g_h1[(size_t)bn*16];
    float xv[FX];
#pragma unroll
    for (int f=0;f<FX;f++) xv[f] = xr[f];
    const int INS = FX + 16;
#pragma unroll
    for (int q=0;q<4;q++) {
      int j = jj*4+q;
      float s = 0.f;
#pragma unroll
      for (int f=0;f<FX;f++) s = fmaf(xv[f], cW[j*INS+f], s);
#pragma unroll
      for (int f=0;f<16;f++) s = fmaf(RH[row][f], cW[j*INS+FX+f], s);
      g_cin[(((size_t)b*16 + j)<<10) + n] = f2bf(s);
    }
  }
}

// ------------- MFMA width-16 pass: P = A @ Y; epilogue per MODE -------------
// MODE 0: Y=g_cin, h1 update + ru_in(cell2). MODE 1: Y=g_cin, h2 update + ru_in(t+1).
// MODE 2: Y=g_cin, h2 update + small_in. MODE 3: Y=g_si, out = tanh(P[:,0:2]+b).
template<int MODE>
__global__ __launch_bounds__(128)
void k_mm16(const float* __restrict__ cb,
            const float* __restrict__ rWn, const float* __restrict__ uWn,
            const float* __restrict__ xnext, const float* __restrict__ gcnW,
            const float* __restrict__ gcnb, float* __restrict__ out) {
  __shared__ u16 As[32][136];
  __shared__ u16 Ys[16][136];
  __shared__ float P[32][17];
  __shared__ float HN[32][17];
  __shared__ float OTH[32][17];
  const int b = blockIdx.y, i0 = blockIdx.x*32, tid = threadIdx.x;
  const int w = tid >> 6, lane = tid & 63, m = lane & 15, quad = lane >> 4;
  const size_t Abase = ((size_t)b*NN + i0)*NN;
  const u16* Yg = (MODE==3 ? g_si : g_cin) + ((size_t)b*16)*NN;
  const int srow = tid >> 2, sq = tid & 3;       // A staging
  const int yrow = tid >> 3, yc = tid & 7;       // Y staging (16 rows)
  f32x4 acc0 = {0.f,0.f,0.f,0.f};

  for (int k0=0;k0<NN;k0+=128) {
    __syncthreads();
#pragma unroll
    for (int q=0;q<4;q++) {
      int off = sq*8 + q*32;
      *(uint4*)&As[srow][off] = *(const uint4*)&g_Ab[Abase + (size_t)srow*NN + k0 + off];
    }
#pragma unroll
    for (int q=0;q<2;q++) {
      int off = yc*8 + q*64;
      *(uint4*)&Ys[yrow][off] = *(const uint4*)&Yg[(size_t)yrow*NN + k0 + off];
    }
    __syncthreads();
#pragma unroll
    for (int s=0;s<4;s++) {
      bf16x8 af = *(const bf16x8*)&As[w*16 + m][s*32 + quad*8];
      bf16x8 bf = *(const bf16x8*)&Ys[m]      [s*32 + quad*8];
      acc0 = __builtin_amdgcn_mfma_f32_16x16x32_bf16(af, bf, acc0, 0, 0, 0);
    }
  }
#pragma unroll
  for (int r=0;r<4;r++) P[w*16 + quad*4 + r][m] = acc0[r];
  __syncthreads();

  const int row = tid >> 2, jj = tid & 3, n = i0 + row, bn = b*NN + n;
  if (MODE == 3) {
    if (jj == 0) {
      float2 o = make_float2(tanhf(P[row][0] + gcnb[0]), tanhf(P[row][1] + gcnb[1]));
      *(float2*)&out[((size_t)b*NN + n)*FF] = o;
    }
    return;
  }
  float* hb = (MODE==0) ? &g_h1[(size_t)bn*16] : &g_h2[(size_t)bn*16];
  {
    float4 hov = *(const float4*)&hb[jj*4];
    float ho[4] = {hov.x,hov.y,hov.z,hov.w};
    float4 uv4 = *(const float4*)&g_u[(size_t)bn*16 + jj*4];
    float uv[4] = {uv4.x,uv4.y,uv4.z,uv4.w};
    float hn[4];
#pragma unroll
    for (int q=0;q<4;q++) {
      int j = jj*4+q;
      float cv = tanhf(P[row][j] + cb[j]);
      hn[q] = uv[q]*ho[q] + (1.f-uv[q])*cv;
      HN[row][j] = hn[q];
    }
    *(float4*)&hb[jj*4] = make_float4(hn[0],hn[1],hn[2],hn[3]);
    if (MODE == 0) {
      float4 o = *(const float4*)&g_h2[(size_t)bn*16 + jj*4];
      OTH[row][jj*4+0]=o.x; OTH[row][jj*4+1]=o.y; OTH[row][jj*4+2]=o.z; OTH[row][jj*4+3]=o.w;
    } else if (MODE == 1) {
      float4 o = *(const float4*)&g_h1[(size_t)bn*16 + jj*4];
      OTH[row][jj*4+0]=o.x; OTH[row][jj*4+1]=o.y; OTH[row][jj*4+2]=o.z; OTH[row][jj*4+3]=o.w;
    }
  }
  __syncthreads();
  if (MODE == 0) {
#pragma unroll
    for (int m2=0;m2<8;m2++) {
      int j2 = jj*8 + m2;
      const float* W = (j2<16) ? (rWn + j2*32) : (uWn + (j2-16)*32);
      float s = 0.f;
#pragma unroll
      for (int f=0;f<16;f++) s = fmaf(HN[row][f], W[f], s);
#pragma unroll
      for (int f=0;f<16;f++) s = fmaf(OTH[row][f], W[16+f], s);
      g_ru[(((size_t)b*32 + j2)<<10) + n] = f2bf(s);
    }
  } else if (MODE == 1) {
    const float* xr = xnext + (size_t)b*TT*NN*FF + (size_t)n*FF;
    float x0 = xr[0], x1 = xr[1];
#pragma unroll
    for (int m2=0;m2<8;m2++) {
      int j2 = jj*8 + m2;
      const float* W = (j2<16) ? (rWn + j2*18) : (uWn + (j2-16)*18);
      float s = fmaf(x0, W[0], x1*W[1]);
#pragma unroll
      for (int f=0;f<16;f++) s = fmaf(OTH[row][f], W[2+f], s);
      g_ru[(((size_t)b*32 + j2)<<10) + n] = f2bf(s);
    }
  } else {  // MODE 2: small_in rows 0,1 real, 2..15 zero
#pragma unroll
    for (int q=0;q<4;q++) {
      int jl = jj*4+q;
      float s = 0.f;
      if (jl < FF) {
        s = g_c2[b*FF + jl];
#pragma unroll
        for (int f=0;f<16;f++) s = fmaf(HN[row][f], gcnW[jl*80+f], s);
      }
      g_si[(((size_t)b*16 + jl)<<10) + n] = f2bf(s);
    }
  }
}

extern "C" void kernel_launch(void* const* d_in, const int* in_sizes, int n_in,
                              void* d_out, int out_size, void* d_ws, size_t ws_size,
                              hipStream_t stream) {
  (void)in_sizes; (void)n_in; (void)d_ws; (void)ws_size; (void)out_size;
  const float* recent = (const float*)d_in[0];
  const float* trend  = (const float*)d_in[1];
  const float* A      = (const float*)d_in[2];
  const float* tfeat  = (const float*)d_in[3];
  const float* g1rW = (const float*)d_in[4];  const float* g1rb = (const float*)d_in[5];
  const float* g1uW = (const float*)d_in[6];  const float* g1ub = (const float*)d_in[7];
  const float* g1cW = (const float*)d_in[8];  const float* g1cb = (const float*)d_in[9];
  const float* g2rW = (const float*)d_in[10]; const float* g2rb = (const float*)d_in[11];
  const float* g2uW = (const float*)d_in[12]; const float* g2ub = (const float*)d_in[13];
  const float* g2cW = (const float*)d_in[14]; const float* g2cb = (const float*)d_in[15];
  const float* Wih0 = (const float*)d_in[16]; const float* Whh0 = (const float*)d_in[17];
  const float* bih0 = (const float*)d_in[18]; const float* bhh0 = (const float*)d_in[19];
  const float* Wih1 = (const float*)d_in[20]; const float* Whh1 = (const float*)d_in[21];
  const float* bih1 = (const float*)d_in[22]; const float* bhh1 = (const float*)d_in[23];
  const float* ffW  = (const float*)d_in[24]; const float* ffb  = (const float*)d_in[25];
  const float* gcnW = (const float*)d_in[26]; const float* gcnb = (const float*)d_in[27];
  float* out = (float*)d_out;

  k_convert<<<16384, 256, 0, stream>>>(A);
  k_lstm<<<BB, 128, 0, stream>>>(trend, tfeat, Wih0, Whh0, bih0, bhh0,
                                 Wih1, Whh1, bih1, bhh1, ffW, ffb, gcnW);
  k_init<<<(BB*NN)/256, 256, 0, stream>>>(recent, g1rW, g1uW);

  for (int t=0; t<TT; t++) {
    k_mm32<2,1><<<dim3(32,BB), 128, 0, stream>>>(recent + (size_t)t*NN*FF, g1rb, g1ub, g1cW);
    k_mm16<0><<<dim3(32,BB), 128, 0, stream>>>(g1cb, g2rW, g2uW, nullptr, nullptr, nullptr, nullptr);
    k_mm32<16,2><<<dim3(32,BB), 128, 0, stream>>>(nullptr, g2rb, g2ub, g2cW);
    if (t < TT-1)
      k_mm16<1><<<dim3(32,BB), 128, 0, stream>>>(g2cb, g1rW, g1uW, recent + (size_t)(t+1)*NN*FF, nullptr, nullptr, nullptr);
    else
      k_mm16<2><<<dim3(32,BB), 128, 0, stream>>>(g2cb, nullptr, nullptr, nullptr, gcnW, nullptr, nullptr);
  }
  k_mm16<3><<<dim3(32,BB), 128, 0, stream>>>(nullptr, nullptr, nullptr, nullptr, nullptr, gcnb, out);
}